// Round 2
// baseline (193.860 us; speedup 1.0000x reference)
//
#include <hip/hip_runtime.h>
#include <hip/hip_bf16.h>

#define NUM_CLASSES 100000
#define DIM 256
#define BATCH 256
#define NUM_TRUE 1024
#define NUM_SAMPLED 16384
// ln(NUM_CLASSES + 1)
#define LOG_RANGE 11.51293546492023f
#define INV_LOG_RANGE (1.0f / LOG_RANGE)

#define SBLOCKS 128   // sampled blocks (4 tiles x 32 s-rows each), scheduled FIRST
#define STILES  4     // s-tiles per sampled block
#define TBLOCKS 2048  // true blocks (128 labels each) -> grid 2176 > residency, refill smooths tail

typedef __bf16 bf16x8 __attribute__((ext_vector_type(8)));
typedef float  f32x4  __attribute__((ext_vector_type(4)));

// RNE float -> bf16 bits
static __device__ __forceinline__ unsigned short f2bf(float f) {
    unsigned int u = __float_as_uint(f);
    unsigned int lsb = (u >> 16) & 1u;
    u += 0x7fffu + lsb;
    return (unsigned short)(u >> 16);
}

// -log(expected_count(id)), precise libm (once per class, comb_kernel only)
static __device__ __forceinline__ float neg_log_ec(int id) {
    float idf = (float)id;
    float p = logf((idf + 2.0f) / (idf + 1.0f)) * INV_LOG_RANGE;
    float ec = -expm1f((float)NUM_SAMPLED * log1pf(-p));
    return -logf(ec);
}

static __device__ __forceinline__ float dot4(float4 a, float4 b) {
    return fmaf(a.x, b.x, fmaf(a.y, b.y, fmaf(a.z, b.z, a.w * b.w)));
}

// ---- comb[c] = bias[c] - log(ec(c)); inputs fp32 -> bf16; zero out[] ----
__global__ __launch_bounds__(256) void comb_kernel(const float* __restrict__ bias,
                                                   const float* __restrict__ inputs,
                                                   float* __restrict__ comb,
                                                   unsigned short* __restrict__ inbf,
                                                   float* __restrict__ out) {
    int c = blockIdx.x * 256 + threadIdx.x;
    if (c < NUM_CLASSES) comb[c] = bias[c] + neg_log_ec(c);
    if (c < BATCH * DIM) inbf[c] = f2bf(inputs[c]);
    if (c < BATCH) out[c] = 0.0f;   // ordered before fused_kernel on the stream
}

// ---------------- fused kernel: sampled blocks first, then true ----------------
// Final per-batch sums accumulate straight into out[] via fp32 atomics.
// Sampled blocks fold 4 tiles in LDS before touching out -> 33K total atomics.
__global__ __launch_bounds__(256) void fused_kernel(const float* __restrict__ inputs,
                                                    const float* __restrict__ w,
                                                    const float* __restrict__ comb,
                                                    const int* __restrict__ labels,
                                                    const int* __restrict__ sampled,
                                                    const unsigned short* __restrict__ inbf,
                                                    float* __restrict__ out) {
    __shared__ unsigned short lw[32][264];   // w s-tile, bf16 (16.9 KB)
    __shared__ float cs[32];
    __shared__ float bacc[BATCH];
    __shared__ __align__(16) float ins[DIM];
    __shared__ float wsum[4];

    const int tid = threadIdx.x;

    if (blockIdx.x < SBLOCKS) {
        // ============ sampled path: 4 tiles of (32 s-rows x 256 batch) ============
        const int sblk = blockIdx.x;
        bacc[tid] = 0.0f;

        const int inner = tid & 15;
        const int r16   = tid >> 4;
        const int lane  = tid & 63;
        const int wv    = tid >> 6;
        const int m     = lane & 15;
        const int quad  = lane >> 4;
        const int shalf = (wv >> 1) * 16;    // which 16 s-rows
        const int bhalf = (wv & 1) * 128;    // which 128 batch cols

        for (int tt = 0; tt < STILES; ++tt) {
            const int s0 = (sblk * STILES + tt) * 32;

            // stage 32 w rows -> bf16 LDS (per wave-load: 4 rows x 256B = 16 lines)
            #pragma unroll
            for (int rb = 0; rb < 2; ++rb) {
                const int r = rb * 16 + r16;
                const int id = sampled[s0 + r];
                const float* src = w + (size_t)id * DIM;
                #pragma unroll
                for (int j = 0; j < 4; ++j) {
                    float4 v = *(const float4*)(src + j * 64 + inner * 4);
                    ushort4 pk;
                    pk.x = f2bf(v.x); pk.y = f2bf(v.y); pk.z = f2bf(v.z); pk.w = f2bf(v.w);
                    *(ushort4*)(&lw[r][j * 64 + inner * 4]) = pk;
                }
            }
            if (tid < 32) cs[tid] = comb[sampled[s0 + tid]];
            __syncthreads();

            // A-fragments for this wave's 16 s-rows, all K (8 kk): 32 VGPRs
            bf16x8 af[8];
            #pragma unroll
            for (int kk = 0; kk < 8; ++kk)
                af[kk] = *(const bf16x8*)(&lw[shalf + m][kk * 32 + quad * 8]);

            #pragma unroll
            for (int t = 0; t < 8; ++t) {
                const int brow = bhalf + t * 16 + m;
                const unsigned short* bp = inbf + brow * DIM;
                bf16x8 bf[8];
                #pragma unroll
                for (int kk = 0; kk < 8; ++kk)
                    bf[kk] = *(const bf16x8*)(bp + kk * 32 + quad * 8);
                f32x4 acc = {0, 0, 0, 0};
                #pragma unroll
                for (int kk = 0; kk < 8; ++kk)
                    acc = __builtin_amdgcn_mfma_f32_16x16x32_bf16(af[kk], bf[kk], acc, 0, 0, 0);
                // C/D: row(s) = quad*4 + r, col(b) = m
                float ps = 0.0f;
                #pragma unroll
                for (int r = 0; r < 4; ++r) {
                    float c = cs[shalf + quad * 4 + r];
                    float l = acc[r] + c;
                    ps += fmaxf(l, 0.0f) + __logf(1.0f + __expf(-fabsf(l)));
                }
                ps += __shfl_xor(ps, 16); ps += __shfl_xor(ps, 32);
                if (quad == 0) atomicAdd(&bacc[bhalf + t * 16 + m], ps);
            }
            __syncthreads();   // lw/cs reuse barrier; also makes bacc adds visible
        }
        atomicAdd(&out[tid], bacc[tid]);     // one global accumulate per block
    } else {
        // ================= true path: 16 lanes/label, depth-2 pipeline =========
        // 128 labels per block (8 chunks per batch row)
        const int bid  = blockIdx.x - SBLOCKS;
        const int b    = bid >> 3;
        const int chnk = bid & 7;
        ins[tid] = inputs[b * DIM + tid];
        __syncthreads();

        const int lane = tid & 63;
        const int wv   = tid >> 6;
        const int sub  = lane >> 4;
        const int part = lane & 15;
        const float4* ir = (const float4*)ins;
        const float4 in0 = ir[part], in1 = ir[16 + part], in2 = ir[32 + part], in3 = ir[48 + part];

        const int* lab = labels + b * NUM_TRUE + chnk * 128 + wv * 32;

        float4 buf[2][4];
        float  cb[2];
        #pragma unroll
        for (int s = 0; s < 2; ++s) {
            int l = lab[s * 4 + sub];
            const float4* wr = (const float4*)(w + (size_t)l * DIM);
            buf[s][0] = wr[part];      buf[s][1] = wr[16 + part];
            buf[s][2] = wr[32 + part]; buf[s][3] = wr[48 + part];
            cb[s] = comb[l];
        }

        float acc = 0.0f;
        #pragma unroll
        for (int i = 0; i < 8; ++i) {
            const int cur = i & 1;
            float4 w0 = buf[cur][0], w1 = buf[cur][1], w2 = buf[cur][2], w3 = buf[cur][3];
            float cl = cb[cur];
            if (i < 6) {
                int l = lab[(i + 2) * 4 + sub];
                const float4* wr = (const float4*)(w + (size_t)l * DIM);
                buf[cur][0] = wr[part];      buf[cur][1] = wr[16 + part];
                buf[cur][2] = wr[32 + part]; buf[cur][3] = wr[48 + part];
                cb[cur] = comb[l];
            }
            float d = dot4(w0, in0) + dot4(w1, in1) + dot4(w2, in2) + dot4(w3, in3);
            d += __shfl_xor(d, 1); d += __shfl_xor(d, 2);
            d += __shfl_xor(d, 4); d += __shfl_xor(d, 8);
            float logit = d + cl;
            float v = fmaxf(logit, 0.0f) - logit * (1.0f / (float)NUM_TRUE)
                    + __logf(1.0f + __expf(-fabsf(logit)));
            acc += (part == 0) ? v : 0.0f;
        }
        acc += __shfl_xor(acc, 16); acc += __shfl_xor(acc, 32);
        if (lane == 0) wsum[wv] = acc;
        __syncthreads();
        if (tid == 0) atomicAdd(&out[b], wsum[0] + wsum[1] + wsum[2] + wsum[3]);
    }
}

extern "C" void kernel_launch(void* const* d_in, const int* in_sizes, int n_in,
                              void* d_out, int out_size, void* d_ws, size_t ws_size,
                              hipStream_t stream) {
    const float* inputs  = (const float*)d_in[0];   // [256,256]
    const float* w       = (const float*)d_in[1];   // [100000,256]
    const float* bias    = (const float*)d_in[2];   // [100000]
    const int*   labels  = (const int*)d_in[3];     // [256,1024]
    const int*   sampled = (const int*)d_in[4];     // [16384]
    float* out = (float*)d_out;                     // [256]

    float*          comb = (float*)d_ws;                             // 400000 B
    unsigned short* inbf = (unsigned short*)((char*)d_ws + 409600);  // 128 KB

    comb_kernel<<<(NUM_CLASSES + 255) / 256, 256, 0, stream>>>(bias, inputs, comb, inbf, out);
    fused_kernel<<<SBLOCKS + TBLOCKS, 256, 0, stream>>>(inputs, w, comb, labels,
                                                        sampled, inbf, out);
}

// Round 3
// 188.882 us; speedup vs baseline: 1.0264x; 1.0264x over previous
//
#include <hip/hip_runtime.h>
#include <hip/hip_bf16.h>

#define NUM_CLASSES 100000
#define DIM 256
#define BATCH 256
#define NUM_TRUE 1024
#define NUM_SAMPLED 16384
// ln(NUM_CLASSES + 1)
#define LOG_RANGE 11.51293546492023f
#define INV_LOG_RANGE (1.0f / LOG_RANGE)

#define SBLOCKS 512   // sampled blocks (32 s-rows each), scheduled FIRST
#define TBLOCKS 2048  // true blocks (128 labels each) -> grid 2560, refill smooths tail

typedef __bf16 bf16x8 __attribute__((ext_vector_type(8)));
typedef float  f32x4  __attribute__((ext_vector_type(4)));

// RNE float -> bf16 bits
static __device__ __forceinline__ unsigned short f2bf(float f) {
    unsigned int u = __float_as_uint(f);
    unsigned int lsb = (u >> 16) & 1u;
    u += 0x7fffu + lsb;
    return (unsigned short)(u >> 16);
}

// -log(expected_count(id)), precise libm (once per class, comb_kernel only)
static __device__ __forceinline__ float neg_log_ec(int id) {
    float idf = (float)id;
    float p = logf((idf + 2.0f) / (idf + 1.0f)) * INV_LOG_RANGE;
    float ec = -expm1f((float)NUM_SAMPLED * log1pf(-p));
    return -logf(ec);
}

static __device__ __forceinline__ float dot4(float4 a, float4 b) {
    return fmaf(a.x, b.x, fmaf(a.y, b.y, fmaf(a.z, b.z, a.w * b.w)));
}

// ---- comb[c] = bias[c] - log(ec(c)); inputs fp32 -> bf16; zero out[] ----
__global__ __launch_bounds__(256) void comb_kernel(const float* __restrict__ bias,
                                                   const float* __restrict__ inputs,
                                                   float* __restrict__ comb,
                                                   unsigned short* __restrict__ inbf,
                                                   float* __restrict__ out) {
    int c = blockIdx.x * 256 + threadIdx.x;
    if (c < NUM_CLASSES) comb[c] = bias[c] + neg_log_ec(c);
    if (c < BATCH * DIM) inbf[c] = f2bf(inputs[c]);
    if (c < BATCH) out[c] = 0.0f;   // ordered before fused_kernel on the stream
}

// ---------------- fused kernel: sampled blocks first, then true ----------------
// Round-0 structure (single s-tile per block, VGPR ~68) + direct out-atomics
// (reduce kernel and partial/truep round-trips deleted).
__global__ __launch_bounds__(256) void fused_kernel(const float* __restrict__ inputs,
                                                    const float* __restrict__ w,
                                                    const float* __restrict__ comb,
                                                    const int* __restrict__ labels,
                                                    const int* __restrict__ sampled,
                                                    const unsigned short* __restrict__ inbf,
                                                    float* __restrict__ out) {
    __shared__ unsigned short lw[32][264];   // w s-tile, bf16 (16.9 KB)
    __shared__ float cs[32];
    __shared__ float bacc[BATCH];
    __shared__ __align__(16) float ins[DIM];
    __shared__ float wsum[4];

    const int tid = threadIdx.x;

    if (blockIdx.x < SBLOCKS) {
        // ================= sampled path: 32 s-rows x 256 batch =================
        const int sblk = blockIdx.x;
        const int s0 = sblk * 32;
        bacc[tid] = 0.0f;

        // stage 32 w rows -> bf16 LDS (per wave-load: 4 rows x 256B = 16 lines)
        const int inner = tid & 15;
        const int r16   = tid >> 4;
        #pragma unroll
        for (int rb = 0; rb < 2; ++rb) {
            const int r = rb * 16 + r16;
            const int id = sampled[s0 + r];
            const float* src = w + (size_t)id * DIM;
            #pragma unroll
            for (int j = 0; j < 4; ++j) {
                float4 v = *(const float4*)(src + j * 64 + inner * 4);
                ushort4 pk;
                pk.x = f2bf(v.x); pk.y = f2bf(v.y); pk.z = f2bf(v.z); pk.w = f2bf(v.w);
                *(ushort4*)(&lw[r][j * 64 + inner * 4]) = pk;
            }
        }
        if (tid < 32) cs[tid] = comb[sampled[s0 + tid]];
        __syncthreads();

        const int lane = tid & 63;
        const int wv   = tid >> 6;
        const int m    = lane & 15;
        const int quad = lane >> 4;
        const int shalf = (wv >> 1) * 16;    // which 16 s-rows
        const int bhalf = (wv & 1) * 128;    // which 128 batch cols

        // A-fragments for this wave's 16 s-rows, all K (8 kk): 32 VGPRs
        bf16x8 af[8];
        #pragma unroll
        for (int kk = 0; kk < 8; ++kk)
            af[kk] = *(const bf16x8*)(&lw[shalf + m][kk * 32 + quad * 8]);

        #pragma unroll
        for (int t = 0; t < 8; ++t) {
            const int brow = bhalf + t * 16 + m;
            const unsigned short* bp = inbf + brow * DIM;
            bf16x8 bf[8];
            #pragma unroll
            for (int kk = 0; kk < 8; ++kk)
                bf[kk] = *(const bf16x8*)(bp + kk * 32 + quad * 8);
            f32x4 acc = {0, 0, 0, 0};
            #pragma unroll
            for (int kk = 0; kk < 8; ++kk)
                acc = __builtin_amdgcn_mfma_f32_16x16x32_bf16(af[kk], bf[kk], acc, 0, 0, 0);
            // C/D: row(s) = quad*4 + r, col(b) = m
            float ps = 0.0f;
            #pragma unroll
            for (int r = 0; r < 4; ++r) {
                float c = cs[shalf + quad * 4 + r];
                float l = acc[r] + c;
                ps += fmaxf(l, 0.0f) + __logf(1.0f + __expf(-fabsf(l)));
            }
            ps += __shfl_xor(ps, 16); ps += __shfl_xor(ps, 32);
            if (quad == 0) atomicAdd(&bacc[bhalf + t * 16 + m], ps);
        }
        __syncthreads();
        atomicAdd(&out[tid], bacc[tid]);     // one global accumulate per thread
    } else {
        // ================= true path: 16 lanes/label, depth-2 pipeline =========
        // 128 labels per block (8 chunks per batch row)
        const int bid  = blockIdx.x - SBLOCKS;
        const int b    = bid >> 3;
        const int chnk = bid & 7;
        ins[tid] = inputs[b * DIM + tid];
        __syncthreads();

        const int lane = tid & 63;
        const int wv   = tid >> 6;
        const int sub  = lane >> 4;
        const int part = lane & 15;
        const float4* ir = (const float4*)ins;
        const float4 in0 = ir[part], in1 = ir[16 + part], in2 = ir[32 + part], in3 = ir[48 + part];

        const int* lab = labels + b * NUM_TRUE + chnk * 128 + wv * 32;

        float4 buf[2][4];
        float  cb[2];
        #pragma unroll
        for (int s = 0; s < 2; ++s) {
            int l = lab[s * 4 + sub];
            const float4* wr = (const float4*)(w + (size_t)l * DIM);
            buf[s][0] = wr[part];      buf[s][1] = wr[16 + part];
            buf[s][2] = wr[32 + part]; buf[s][3] = wr[48 + part];
            cb[s] = comb[l];
        }

        float acc = 0.0f;
        #pragma unroll
        for (int i = 0; i < 8; ++i) {
            const int cur = i & 1;
            float4 w0 = buf[cur][0], w1 = buf[cur][1], w2 = buf[cur][2], w3 = buf[cur][3];
            float cl = cb[cur];
            if (i < 6) {
                int l = lab[(i + 2) * 4 + sub];
                const float4* wr = (const float4*)(w + (size_t)l * DIM);
                buf[cur][0] = wr[part];      buf[cur][1] = wr[16 + part];
                buf[cur][2] = wr[32 + part]; buf[cur][3] = wr[48 + part];
                cb[cur] = comb[l];
            }
            float d = dot4(w0, in0) + dot4(w1, in1) + dot4(w2, in2) + dot4(w3, in3);
            d += __shfl_xor(d, 1); d += __shfl_xor(d, 2);
            d += __shfl_xor(d, 4); d += __shfl_xor(d, 8);
            float logit = d + cl;
            float v = fmaxf(logit, 0.0f) - logit * (1.0f / (float)NUM_TRUE)
                    + __logf(1.0f + __expf(-fabsf(logit)));
            acc += (part == 0) ? v : 0.0f;
        }
        acc += __shfl_xor(acc, 16); acc += __shfl_xor(acc, 32);
        if (lane == 0) wsum[wv] = acc;
        __syncthreads();
        if (tid == 0) atomicAdd(&out[b], wsum[0] + wsum[1] + wsum[2] + wsum[3]);
    }
}

extern "C" void kernel_launch(void* const* d_in, const int* in_sizes, int n_in,
                              void* d_out, int out_size, void* d_ws, size_t ws_size,
                              hipStream_t stream) {
    const float* inputs  = (const float*)d_in[0];   // [256,256]
    const float* w       = (const float*)d_in[1];   // [100000,256]
    const float* bias    = (const float*)d_in[2];   // [100000]
    const int*   labels  = (const int*)d_in[3];     // [256,1024]
    const int*   sampled = (const int*)d_in[4];     // [16384]
    float* out = (float*)d_out;                     // [256]

    float*          comb = (float*)d_ws;                             // 400000 B
    unsigned short* inbf = (unsigned short*)((char*)d_ws + 409600);  // 128 KB

    comb_kernel<<<(NUM_CLASSES + 255) / 256, 256, 0, stream>>>(bias, inputs, comb, inbf, out);
    fused_kernel<<<SBLOCKS + TBLOCKS, 256, 0, stream>>>(inputs, w, comb, labels,
                                                        sampled, inbf, out);
}

// Round 5
// 180.185 us; speedup vs baseline: 1.0759x; 1.0483x over previous
//
#include <hip/hip_runtime.h>
#include <hip/hip_bf16.h>

#define NUM_CLASSES 100000
#define DIM 256
#define BATCH 256
#define NUM_TRUE 1024
#define NUM_SAMPLED 16384
// ln(NUM_CLASSES + 1)
#define LOG_RANGE 11.51293546492023f
#define INV_LOG_RANGE (1.0f / LOG_RANGE)

#define SBLOCKS 512   // sampled blocks (32 s-rows each), scheduled FIRST
#define TBLOCKS 2048  // true blocks (128 labels each) -> grid 2560, refill smooths tail

typedef __bf16 bf16x8 __attribute__((ext_vector_type(8)));
typedef float  f32x4  __attribute__((ext_vector_type(4)));

// RNE float -> bf16 bits
static __device__ __forceinline__ unsigned short f2bf(float f) {
    unsigned int u = __float_as_uint(f);
    unsigned int lsb = (u >> 16) & 1u;
    u += 0x7fffu + lsb;
    return (unsigned short)(u >> 16);
}

// -log(expected_count(id)), precise libm (once per class, comb_kernel only)
static __device__ __forceinline__ float neg_log_ec(int id) {
    float idf = (float)id;
    float p = logf((idf + 2.0f) / (idf + 1.0f)) * INV_LOG_RANGE;
    float ec = -expm1f((float)NUM_SAMPLED * log1pf(-p));
    return -logf(ec);
}

static __device__ __forceinline__ float dot4(float4 a, float4 b) {
    return fmaf(a.x, b.x, fmaf(a.y, b.y, fmaf(a.z, b.z, a.w * b.w)));
}

// ---- comb[c] = bias[c] - log(ec(c)); inputs fp32 -> bf16 ----
__global__ __launch_bounds__(256) void comb_kernel(const float* __restrict__ bias,
                                                   const float* __restrict__ inputs,
                                                   float* __restrict__ comb,
                                                   unsigned short* __restrict__ inbf) {
    int c = blockIdx.x * 256 + threadIdx.x;
    if (c < NUM_CLASSES) comb[c] = bias[c] + neg_log_ec(c);
    if (c < BATCH * DIM) inbf[c] = f2bf(inputs[c]);
}

// ---------------- fused kernel: sampled blocks first, then true ----------------
// Output via non-atomic partial writes (R0 scheme, proven faster than out-atomics).
// True path: labels+comb preloaded into registers, broadcast via __shfl ->
// inner loop has only the independent depth-2 row gathers (no dependent chain).
__global__ __launch_bounds__(256) void fused_kernel(const float* __restrict__ inputs,
                                                    const float* __restrict__ w,
                                                    const float* __restrict__ comb,
                                                    const int* __restrict__ labels,
                                                    const int* __restrict__ sampled,
                                                    const unsigned short* __restrict__ inbf,
                                                    float* __restrict__ truep,
                                                    float* __restrict__ partial) {
    __shared__ unsigned short lw[32][264];   // w s-tile, bf16 (16.9 KB)
    __shared__ float cs[32];
    __shared__ float bacc[BATCH];
    __shared__ __align__(16) float ins[DIM];
    __shared__ float wsum[4];

    const int tid = threadIdx.x;

    if (blockIdx.x < SBLOCKS) {
        // ================= sampled path: 32 s-rows x 256 batch =================
        const int sblk = blockIdx.x;
        const int s0 = sblk * 32;
        bacc[tid] = 0.0f;

        // stage 32 w rows -> bf16 LDS (per wave-load: 4 rows x 256B = 16 lines)
        const int inner = tid & 15;
        const int r16   = tid >> 4;
        #pragma unroll
        for (int rb = 0; rb < 2; ++rb) {
            const int r = rb * 16 + r16;
            const int id = sampled[s0 + r];
            const float* src = w + (size_t)id * DIM;
            #pragma unroll
            for (int j = 0; j < 4; ++j) {
                float4 v = *(const float4*)(src + j * 64 + inner * 4);
                ushort4 pk;
                pk.x = f2bf(v.x); pk.y = f2bf(v.y); pk.z = f2bf(v.z); pk.w = f2bf(v.w);
                *(ushort4*)(&lw[r][j * 64 + inner * 4]) = pk;
            }
        }
        if (tid < 32) cs[tid] = comb[sampled[s0 + tid]];
        __syncthreads();

        const int lane = tid & 63;
        const int wv   = tid >> 6;
        const int m    = lane & 15;
        const int quad = lane >> 4;
        const int shalf = (wv >> 1) * 16;    // which 16 s-rows
        const int bhalf = (wv & 1) * 128;    // which 128 batch cols

        // A-fragments for this wave's 16 s-rows, all K (8 kk): 32 VGPRs
        bf16x8 af[8];
        #pragma unroll
        for (int kk = 0; kk < 8; ++kk)
            af[kk] = *(const bf16x8*)(&lw[shalf + m][kk * 32 + quad * 8]);

        #pragma unroll
        for (int t = 0; t < 8; ++t) {
            const int brow = bhalf + t * 16 + m;
            const unsigned short* bp = inbf + brow * DIM;
            bf16x8 bf[8];
            #pragma unroll
            for (int kk = 0; kk < 8; ++kk)
                bf[kk] = *(const bf16x8*)(bp + kk * 32 + quad * 8);
            f32x4 acc = {0, 0, 0, 0};
            #pragma unroll
            for (int kk = 0; kk < 8; ++kk)
                acc = __builtin_amdgcn_mfma_f32_16x16x32_bf16(af[kk], bf[kk], acc, 0, 0, 0);
            // C/D: row(s) = quad*4 + r, col(b) = m
            float ps = 0.0f;
            #pragma unroll
            for (int r = 0; r < 4; ++r) {
                float c = cs[shalf + quad * 4 + r];
                float l = acc[r] + c;
                ps += fmaxf(l, 0.0f) + __logf(1.0f + __expf(-fabsf(l)));
            }
            ps += __shfl_xor(ps, 16); ps += __shfl_xor(ps, 32);
            if (quad == 0) atomicAdd(&bacc[bhalf + t * 16 + m], ps);
        }
        __syncthreads();
        partial[tid * SBLOCKS + sblk] = bacc[tid];   // [b][sblk], non-atomic
    } else {
        // ================= true path: 16 lanes/label, depth-2 pipeline =========
        // 128 labels per block (8 chunks per batch row)
        const int bid  = blockIdx.x - SBLOCKS;
        const int b    = bid >> 3;
        const int chnk = bid & 7;
        ins[tid] = inputs[b * DIM + tid];
        __syncthreads();

        const int lane = tid & 63;
        const int wv   = tid >> 6;
        const int sub  = lane >> 4;
        const int part = lane & 15;
        const float4* ir = (const float4*)ins;
        const float4 in0 = ir[part], in1 = ir[16 + part], in2 = ir[32 + part], in3 = ir[48 + part];

        const int* lab = labels + b * NUM_TRUE + chnk * 128 + wv * 32;

        // preload all 32 labels of this wave + their comb values into registers
        const int   l_pre = lab[lane & 31];
        const float c_pre = comb[l_pre];

        float4 buf[2][4];
        #pragma unroll
        for (int s = 0; s < 2; ++s) {
            int l = __shfl(l_pre, s * 4 + sub);
            const float4* wr = (const float4*)(w + (size_t)l * DIM);
            buf[s][0] = wr[part];      buf[s][1] = wr[16 + part];
            buf[s][2] = wr[32 + part]; buf[s][3] = wr[48 + part];
        }

        float acc = 0.0f;
        #pragma unroll
        for (int i = 0; i < 8; ++i) {
            const int cur = i & 1;
            float4 w0 = buf[cur][0], w1 = buf[cur][1], w2 = buf[cur][2], w3 = buf[cur][3];
            if (i < 6) {
                int l = __shfl(l_pre, (i + 2) * 4 + sub);
                const float4* wr = (const float4*)(w + (size_t)l * DIM);
                buf[cur][0] = wr[part];      buf[cur][1] = wr[16 + part];
                buf[cur][2] = wr[32 + part]; buf[cur][3] = wr[48 + part];
            }
            float cl = __shfl(c_pre, i * 4 + sub);
            float d = dot4(w0, in0) + dot4(w1, in1) + dot4(w2, in2) + dot4(w3, in3);
            d += __shfl_xor(d, 1); d += __shfl_xor(d, 2);
            d += __shfl_xor(d, 4); d += __shfl_xor(d, 8);
            float logit = d + cl;
            float v = fmaxf(logit, 0.0f) - logit * (1.0f / (float)NUM_TRUE)
                    + __logf(1.0f + __expf(-fabsf(logit)));
            acc += (part == 0) ? v : 0.0f;
        }
        acc += __shfl_xor(acc, 16); acc += __shfl_xor(acc, 32);
        if (lane == 0) wsum[wv] = acc;
        __syncthreads();
        if (tid == 0) truep[b * 8 + chnk] = wsum[0] + wsum[1] + wsum[2] + wsum[3];
    }
}

// ---- final reduce: out[b] = sum_512 sampled partials + sum_8 true partials ----
__global__ __launch_bounds__(256) void reduce_kernel(const float* __restrict__ partial,
                                                     const float* __restrict__ truep,
                                                     float* __restrict__ out) {
    __shared__ float wsum[4];
    const int b = blockIdx.x;
    const int tid = threadIdx.x;
    float v = partial[b * SBLOCKS + tid] + partial[b * SBLOCKS + 256 + tid];
    if (tid < 8) v += truep[b * 8 + tid];
    v += __shfl_xor(v, 1);  v += __shfl_xor(v, 2);  v += __shfl_xor(v, 4);
    v += __shfl_xor(v, 8);  v += __shfl_xor(v, 16); v += __shfl_xor(v, 32);
    if ((tid & 63) == 0) wsum[tid >> 6] = v;
    __syncthreads();
    if (tid == 0) out[b] = wsum[0] + wsum[1] + wsum[2] + wsum[3];
}

extern "C" void kernel_launch(void* const* d_in, const int* in_sizes, int n_in,
                              void* d_out, int out_size, void* d_ws, size_t ws_size,
                              hipStream_t stream) {
    const float* inputs  = (const float*)d_in[0];   // [256,256]
    const float* w       = (const float*)d_in[1];   // [100000,256]
    const float* bias    = (const float*)d_in[2];   // [100000]
    const int*   labels  = (const int*)d_in[3];     // [256,1024]
    const int*   sampled = (const int*)d_in[4];     // [16384]
    float* out = (float*)d_out;                     // [256]

    float*          comb    = (float*)d_ws;                             // 400000 B
    unsigned short* inbf    = (unsigned short*)((char*)d_ws + 409600);  // 128 KB
    float*          truep   = (float*)((char*)d_ws + 540672);           // 8 KB
    float*          partial = (float*)((char*)d_ws + 548864);           // 512 KB

    comb_kernel<<<(NUM_CLASSES + 255) / 256, 256, 0, stream>>>(bias, inputs, comb, inbf);
    fused_kernel<<<SBLOCKS + TBLOCKS, 256, 0, stream>>>(inputs, w, comb, labels,
                                                        sampled, inbf, truep, partial);
    reduce_kernel<<<BATCH, 256, 0, stream>>>(partial, truep, out);
}